// Round 2
// baseline (353.919 us; speedup 1.0000x reference)
//
#include <hip/hip_runtime.h>

// SoftDepthShader: softmax depth blend, N=8 H=256 W=256 K=50.
// 524288 pixels; zbuf/dists f32 + pix_to_face i32, ~315 MB read -> memory-bound.
//
// R2 design: 4 lanes per pixel, no LDS, no __syncthreads.
//   - lane q in [0,4) loads float2 chunks j = q + 4*i (i<6), plus chunk 24 for q=0.
//     Sibling lanes' chunks are contiguous -> 32 B segments per 4 lanes.
//   - two-pass reduce in registers (max tree, then independent exps) breaks the
//     R1 online-softmax serial chain (~1400 dependent cycles/thread).
//   - cross-lane combine via __shfl_xor(1), __shfl_xor(2).

constexpr int THREADS = 256;
constexpr int LPP     = 4;              // lanes per pixel
constexpr int PPB     = THREADS / LPP;  // 64 pixels per block
constexpr int NV      = 14;             // max values per lane (q=0: 14, else 12)

constexpr float INV_SIGMA = 1e4f;       // 1/sigma
constexpr float INVG      = 1e4f;       // 1/gamma
constexpr float ZFAR      = 100.0f;
constexpr float ZRANGE    = 99.0f;      // zfar - znear
constexpr float INV_ZRANGE= 1.0f / 99.0f;
constexpr float EPS       = 1e-10f;

__global__ __launch_bounds__(THREADS) void soft_depth_kernel(
    const float* __restrict__ zbuf,
    const float* __restrict__ dists,
    const int*   __restrict__ p2f,
    float*       __restrict__ out)
{
    const int t  = threadIdx.x;
    const int q  = t & (LPP - 1);
    const size_t pix   = (size_t)blockIdx.x * PPB + (t >> 2);
    const size_t cbase = pix * 25 + q;       // float2-chunk index base (25 chunks/pixel)

    const float2* __restrict__ z2 = (const float2*)zbuf;
    const float2* __restrict__ d2 = (const float2*)dists;
    const int2*   __restrict__ f2 = (const int2*)p2f;

    float zv[NV];   // masked z_inv
    float pv[NV];   // masked prob = sigmoid(-d/sigma)

    #pragma unroll
    for (int i = 0; i < 6; ++i) {
        const size_t c = cbase + 4 * i;
        const float2 z = z2[c];
        const float2 d = d2[c];
        const int2   f = f2[c];
        const bool m0 = (f.x >= 0);
        const bool m1 = (f.y >= 0);
        zv[2*i]   = m0 ? (ZFAR - z.x) * INV_ZRANGE : 0.0f;
        zv[2*i+1] = m1 ? (ZFAR - z.y) * INV_ZRANGE : 0.0f;
        pv[2*i]   = m0 ? 1.0f / (1.0f + __expf(d.x * INV_SIGMA)) : 0.0f;
        pv[2*i+1] = m1 ? 1.0f / (1.0f + __expf(d.y * INV_SIGMA)) : 0.0f;
    }
    // chunk 24 (slots 48,49): only lane q==0; others contribute zeros (w==0).
    if (q == 0) {
        const size_t c = pix * 25 + 24;
        const float2 z = z2[c];
        const float2 d = d2[c];
        const int2   f = f2[c];
        const bool m0 = (f.x >= 0);
        const bool m1 = (f.y >= 0);
        zv[12] = m0 ? (ZFAR - z.x) * INV_ZRANGE : 0.0f;
        zv[13] = m1 ? (ZFAR - z.y) * INV_ZRANGE : 0.0f;
        pv[12] = m0 ? 1.0f / (1.0f + __expf(d.x * INV_SIGMA)) : 0.0f;
        pv[13] = m1 ? 1.0f / (1.0f + __expf(d.y * INV_SIGMA)) : 0.0f;
    } else {
        zv[12] = zv[13] = 0.0f;
        pv[12] = pv[13] = 0.0f;
    }

    // ---- pass 1: max (pairwise tree locally, then 2-step shuffle) ----
    float m01 = fmaxf(zv[0], zv[1]),   m23 = fmaxf(zv[2], zv[3]);
    float m45 = fmaxf(zv[4], zv[5]),   m67 = fmaxf(zv[6], zv[7]);
    float m89 = fmaxf(zv[8], zv[9]),   mab = fmaxf(zv[10], zv[11]);
    float mcd = fmaxf(zv[12], zv[13]);
    float m = fmaxf(fmaxf(fmaxf(m01, m23), fmaxf(m45, m67)),
                    fmaxf(fmaxf(m89, mab), fmaxf(mcd, EPS)));
    m = fmaxf(m, __shfl_xor(m, 1));
    m = fmaxf(m, __shfl_xor(m, 2));   // all 4 lanes now hold max(max_k z_inv, EPS)

    // ---- pass 2: sums (independent exps, split accumulators) ----
    float S1a = 0.0f, S1b = 0.0f, S2a = 0.0f, S2b = 0.0f;
    #pragma unroll
    for (int j = 0; j < NV; j += 2) {
        const float w0 = pv[j]   * __expf((zv[j]   - m) * INVG);
        const float w1 = pv[j+1] * __expf((zv[j+1] - m) * INVG);
        S1a += w0;
        S1b += w1;
        S2a += w0 * (ZFAR - zv[j]   * ZRANGE);   // reconstruct zbuf; w==0 where masked
        S2b += w1 * (ZFAR - zv[j+1] * ZRANGE);
    }
    float S1 = S1a + S1b;
    float S2 = S2a + S2b;
    S1 += __shfl_xor(S1, 1);  S1 += __shfl_xor(S1, 2);
    S2 += __shfl_xor(S2, 1);  S2 += __shfl_xor(S2, 2);

    if (q == 0) {
        const float delta = fmaxf(__expf((EPS - m) * INVG), EPS);
        out[pix] = (S2 + delta) / (S1 + delta);   // BG_BLUE = 1
    }
}

extern "C" void kernel_launch(void* const* d_in, const int* in_sizes, int n_in,
                              void* d_out, int out_size, void* d_ws, size_t ws_size,
                              hipStream_t stream) {
    const float* zbuf  = (const float*)d_in[0];
    const float* dists = (const float*)d_in[1];
    const int*   p2f   = (const int*)d_in[2];
    float* out = (float*)d_out;

    const int pixels = out_size;                 // 524288
    const int blocks = pixels / PPB;             // 8192 (exact)

    soft_depth_kernel<<<dim3(blocks), dim3(THREADS), 0, stream>>>(
        zbuf, dists, p2f, out);
}

// Round 3
// 279.654 us; speedup vs baseline: 1.2656x; 1.2656x over previous
//
#include <hip/hip_runtime.h>

// SoftDepthShader: softmax depth blend, N=8 H=256 W=256 K=50 (524288 pixels).
// ~315 MB read, ~2 MB write -> memory-bound, floor ~50 us at 6.3 TB/s.
//
// R3 design: 8 lanes per pixel (team), float2 chunks c = q + 8i.
//   - Each team instruction covers a contiguous 64 B segment of the pixel row
//     (R2's 32 B segments caused 1.7x HBM over-fetch: FETCH 534 MB vs 315 MB).
//   - ALL loads issued before ANY transform: R2 interleaved __expf with loads
//     and the compiler register-minimized to 28 VGPRs, leaving ~3 loads in
//     flight. Load phase and compute phase are now separate straight-line code.
//   - Tail chunk 24 loaded uniformly by all 8 team lanes (7 redundant 8 B
//     broadcast reads, L1-merged), masked in registers for q != 0.
//   - Reduce: local tree max + __shfl_xor(1,2,4), independent exps, shuffle-add.

constexpr int THREADS = 256;
constexpr int LPP     = 8;              // lanes per pixel (team)
constexpr int PPB     = THREADS / LPP;  // 32 pixels per block

constexpr float INV_SIGMA  = 1e4f;      // 1/sigma
constexpr float INVG       = 1e4f;      // 1/gamma
constexpr float ZFAR       = 100.0f;
constexpr float ZRANGE     = 99.0f;     // zfar - znear
constexpr float INV_ZRANGE = 1.0f / 99.0f;
constexpr float EPS        = 1e-10f;

__global__ __launch_bounds__(THREADS) void soft_depth_kernel(
    const float* __restrict__ zbuf,
    const float* __restrict__ dists,
    const int*   __restrict__ p2f,
    float*       __restrict__ out)
{
    const int t = threadIdx.x;
    const int q = t & (LPP - 1);
    const size_t pix = (size_t)blockIdx.x * PPB + (t >> 3);
    const size_t cb  = pix * 25;        // float2-chunk base (25 chunks/pixel)

    const float2* __restrict__ z2 = (const float2*)zbuf;
    const float2* __restrict__ d2 = (const float2*)dists;
    const int2*   __restrict__ f2 = (const int2*)p2f;

    // ---- phase 1: issue ALL loads (no dependent math in between) ----
    const size_t c0 = cb + q, c1 = cb + q + 8, c2 = cb + q + 16, c3 = cb + 24;
    const float2 za = z2[c0], zb = z2[c1], zc = z2[c2], zd = z2[c3];
    const float2 da = d2[c0], db = d2[c1], dc = d2[c2], dd = d2[c3];
    const int2   fa = f2[c0], fb = f2[c1], fc = f2[c2], fd = f2[c3];

    // ---- phase 2: transform (masked z_inv and prob) ----
    float zv[8], pv[8];
    {
        const bool v3 = (q == 0);       // chunk 24 only belongs to lane q==0
        const bool m0 = (fa.x >= 0),       m1 = (fa.y >= 0);
        const bool m2 = (fb.x >= 0),       m3 = (fb.y >= 0);
        const bool m4 = (fc.x >= 0),       m5 = (fc.y >= 0);
        const bool m6 = v3 && (fd.x >= 0), m7 = v3 && (fd.y >= 0);
        zv[0] = m0 ? (ZFAR - za.x) * INV_ZRANGE : 0.0f;
        zv[1] = m1 ? (ZFAR - za.y) * INV_ZRANGE : 0.0f;
        zv[2] = m2 ? (ZFAR - zb.x) * INV_ZRANGE : 0.0f;
        zv[3] = m3 ? (ZFAR - zb.y) * INV_ZRANGE : 0.0f;
        zv[4] = m4 ? (ZFAR - zc.x) * INV_ZRANGE : 0.0f;
        zv[5] = m5 ? (ZFAR - zc.y) * INV_ZRANGE : 0.0f;
        zv[6] = m6 ? (ZFAR - zd.x) * INV_ZRANGE : 0.0f;
        zv[7] = m7 ? (ZFAR - zd.y) * INV_ZRANGE : 0.0f;
        pv[0] = m0 ? 1.0f / (1.0f + __expf(da.x * INV_SIGMA)) : 0.0f;
        pv[1] = m1 ? 1.0f / (1.0f + __expf(da.y * INV_SIGMA)) : 0.0f;
        pv[2] = m2 ? 1.0f / (1.0f + __expf(db.x * INV_SIGMA)) : 0.0f;
        pv[3] = m3 ? 1.0f / (1.0f + __expf(db.y * INV_SIGMA)) : 0.0f;
        pv[4] = m4 ? 1.0f / (1.0f + __expf(dc.x * INV_SIGMA)) : 0.0f;
        pv[5] = m5 ? 1.0f / (1.0f + __expf(dc.y * INV_SIGMA)) : 0.0f;
        pv[6] = m6 ? 1.0f / (1.0f + __expf(dd.x * INV_SIGMA)) : 0.0f;
        pv[7] = m7 ? 1.0f / (1.0f + __expf(dd.y * INV_SIGMA)) : 0.0f;
    }

    // ---- pass 1: max over team (tree + 3-step shuffle within 8-lane group) ----
    float m = fmaxf(fmaxf(fmaxf(zv[0], zv[1]), fmaxf(zv[2], zv[3])),
                    fmaxf(fmaxf(zv[4], zv[5]), fmaxf(zv[6], zv[7])));
    m = fmaxf(m, __shfl_xor(m, 1));
    m = fmaxf(m, __shfl_xor(m, 2));
    m = fmaxf(m, __shfl_xor(m, 4));
    m = fmaxf(m, EPS);                  // reference: max(max_k z_inv, EPS)

    // ---- pass 2: weight sums (independent exps, split accumulators) ----
    float S1a = 0.0f, S1b = 0.0f, S2a = 0.0f, S2b = 0.0f;
    #pragma unroll
    for (int j = 0; j < 8; j += 2) {
        const float w0 = pv[j]   * __expf((zv[j]   - m) * INVG);
        const float w1 = pv[j+1] * __expf((zv[j+1] - m) * INVG);
        S1a += w0;
        S1b += w1;
        S2a += w0 * (ZFAR - zv[j]   * ZRANGE);   // reconstruct zbuf; w==0 where masked
        S2b += w1 * (ZFAR - zv[j+1] * ZRANGE);
    }
    float S1 = S1a + S1b;
    float S2 = S2a + S2b;
    S1 += __shfl_xor(S1, 1);  S1 += __shfl_xor(S1, 2);  S1 += __shfl_xor(S1, 4);
    S2 += __shfl_xor(S2, 1);  S2 += __shfl_xor(S2, 2);  S2 += __shfl_xor(S2, 4);

    if (q == 0) {
        const float delta = fmaxf(__expf((EPS - m) * INVG), EPS);
        out[pix] = (S2 + delta) / (S1 + delta);   // BG_BLUE = 1
    }
}

extern "C" void kernel_launch(void* const* d_in, const int* in_sizes, int n_in,
                              void* d_out, int out_size, void* d_ws, size_t ws_size,
                              hipStream_t stream) {
    const float* zbuf  = (const float*)d_in[0];
    const float* dists = (const float*)d_in[1];
    const int*   p2f   = (const int*)d_in[2];
    float* out = (float*)d_out;

    const int pixels = out_size;                 // 524288
    const int blocks = pixels / PPB;             // 16384 (exact)

    soft_depth_kernel<<<dim3(blocks), dim3(THREADS), 0, stream>>>(
        zbuf, dists, p2f, out);
}